// Round 12
// baseline (390.370 us; speedup 1.0000x reference)
//
#include <hip/hip_runtime.h>

typedef float floatx4 __attribute__((ext_vector_type(4)));
typedef short bf16x8 __attribute__((ext_vector_type(8)));
typedef const unsigned int __attribute__((address_space(1))) gas_u32;
typedef unsigned int __attribute__((address_space(3))) las_u32;

#if __has_builtin(__builtin_amdgcn_exp2f)
#define EXP2F(x) __builtin_amdgcn_exp2f(x)
#else
#define EXP2F(x) exp2f(x)
#endif

__device__ __forceinline__ unsigned short f2bf(float x) {
    unsigned int u = __float_as_uint(x);
    unsigned int r = u + 0x7fffu + ((u >> 16) & 1u);
    return (unsigned short)(r >> 16);
}

// truncating pack (P>=0; downward bias cancels in O/l ratio).
__device__ __forceinline__ unsigned int pack2bf_t(float lo, float hi) {
#if __has_builtin(__builtin_amdgcn_perm)
    return __builtin_amdgcn_perm(__float_as_uint(hi), __float_as_uint(lo), 0x07060302u);
#else
    return (__float_as_uint(lo) >> 16) | (__float_as_uint(hi) & 0xffff0000u);
#endif
}

__device__ __forceinline__ void g2l16(const void* g, void* l) {
    __builtin_amdgcn_global_load_lds((gas_u32*)(unsigned long long)g,
                                     (las_u32*)(unsigned int)(unsigned long long)l,
                                     16, 0, 0);
}

// fp32 -> bf16, exact-size linear grid (no idle blocks).
__global__ __launch_bounds__(256) void cvt_kernel(
    const float* __restrict__ q, const float* __restrict__ k, const float* __restrict__ v,
    const float* __restrict__ wq, const float* __restrict__ wk, const float* __restrict__ wv,
    const float* __restrict__ wo,
    unsigned short* __restrict__ qb, unsigned short* __restrict__ kb,
    unsigned short* __restrict__ vb, unsigned short* __restrict__ wqb,
    unsigned short* __restrict__ wkb, unsigned short* __restrict__ wvb,
    unsigned short* __restrict__ wob) {
    const int bid = blockIdx.x;
    const float* src;
    unsigned short* dst;
    int off;
    if (bid < 24576) {
        int s = bid >> 13;                       // 0..2
        off = (bid & 8191) * 256 + threadIdx.x;  // < 2097152 exact
        src = (s == 0) ? q : (s == 1) ? k : v;
        dst = (s == 0) ? qb : (s == 1) ? kb : vb;
    } else {
        int r = bid - 24576;
        int s = r >> 10;                         // 0..3
        off = (r & 1023) * 256 + threadIdx.x;    // < 262144 exact
        src = (s == 0) ? wq : (s == 1) ? wk : (s == 2) ? wv : wo;
        dst = (s == 0) ? wqb : (s == 1) ? wkb : (s == 2) ? wvb : wob;
    }
    float4 x = ((const float4*)src)[off];
    ushort4 o;
    o.x = f2bf(x.x); o.y = f2bf(x.y); o.z = f2bf(x.z); o.w = f2bf(x.w);
    ((ushort4*)dst)[off] = o;
}

// Wo fp32 -> bf16 (1M floats). grid 1024. Fallback (small-ws) path only.
__global__ __launch_bounds__(256) void cvt1_kernel(const float* __restrict__ wo,
                                                   unsigned short* __restrict__ wob) {
    int i = blockIdx.x * 256 + threadIdx.x;
    float4 x = ((const float4*)wo)[i];
    ushort4 o;
    o.x = f2bf(x.x); o.y = f2bf(x.y); o.z = f2bf(x.z); o.w = f2bf(x.w);
    ((ushort4*)wob)[i] = o;
}

// -------- 256x128 tile, BK=32, 512 threads (8 waves, 4M x 2N) --------------
// v3: B operand loaded DIRECTLY L2->reg each kt (weight panel is 256KB,
// XCD-local, L2-hot; no reuse benefit from LDS) -> GEMM LDS-port traffic
// halves (42us -> 23us per CU), balancing LDS / L2 / MFMA pipes (~23/23/25us).
// A stays via tri-buffered g2l LDS (48 KB -> 2 blocks/CU), T2 XOR-swizzled.
// Protocol per kt: barrier -> loadB(kt) -> stageA(kt+2) -> vmcnt(2) -> compute.
// vmcnt(2) (leaving only the 2 newest g2l) forces LOADB(kt) AND the previous
// iteration's STAGE_A(kt+1) complete: one wait + one barrier per kt, never
// vmcnt(0) until the 2-iteration tail. Compiler-inserted waits for the
// B-reg->MFMA dependency make correctness robust to instruction reordering.
// OUT_MODE: 0 = fp32 out, 1 = bf16 out scaled,
//           2 = VT transpose (swizzled), 3 = K permuted (swizzled).
template <int OUT_MODE>
__device__ __forceinline__ void gemm256_body(const unsigned short* __restrict__ Asrc,
                                             const unsigned short* __restrict__ W,
                                             const float* __restrict__ bias,
                                             void* __restrict__ Cout,
                                             unsigned short* lds, int m0, int n0,
                                             float scale) {
    constexpr int K = 1024, N = 1024;
    constexpr int BUFS = 256 * 32;          // A-only buffer: 8192 shorts = 16 KB
    const int t = threadIdx.x;
    const int lane = t & 63, w = t >> 6;
    const int lr = lane & 15, quad = lane >> 4;
    const int wrow = (w & 3) * 64, wcol = (w >> 2) * 64;

    // A staging sources: 4 x 16B slots per row (BK=32); source-col pre-swizzled
    // with key (row>>1)&3 so linear LDS dest + XOR'd read is conflict-free.
    const unsigned short* gA[2];
#pragma unroll
    for (int i = 0; i < 2; ++i) {
        int idx = t + 512 * i;          // 0..1023 -> 256 rows x 4 slots
        int row = idx >> 2, sl = idx & 3;
        gA[i] = Asrc + (size_t)(m0 + row) * K + ((sl ^ ((row >> 1) & 3)) * 8);
    }
    // B fragment pointers: direct global (natural layout, no swizzle).
    const unsigned short* gBf[4];
#pragma unroll
    for (int j = 0; j < 4; ++j)
        gBf[j] = W + (size_t)(n0 + wcol + j * 16 + lr) * K + quad * 8;

    auto STAGE = [&](int buf, int kt) {     // 2 g2l per thread per stage
        unsigned short* dst = lds + buf * BUFS;
#pragma unroll
        for (int i = 0; i < 2; ++i)
            g2l16(gA[i] + kt * 32, dst + (w * 64 + i * 512) * 8);
    };

    floatx4 acc[4][4];
#pragma unroll
    for (int i = 0; i < 4; ++i)
#pragma unroll
        for (int j = 0; j < 4; ++j) acc[i][j] = (floatx4){0.f, 0.f, 0.f, 0.f};

    const int sc = (quad ^ ((lr >> 1) & 3)) * 8;   // A read slot (XOR involution)

    auto COMPUTE = [&](int buf, const bf16x8* bfr) {
        const unsigned short* Ab = lds + buf * BUFS;
        bf16x8 af[4];
#pragma unroll
        for (int i = 0; i < 4; ++i)
            af[i] = *(const bf16x8*)&Ab[(wrow + i * 16 + lr) * 32 + sc];
#pragma unroll
        for (int i = 0; i < 4; ++i)
#pragma unroll
            for (int j = 0; j < 4; ++j) {
                if constexpr (OUT_MODE == 2)
                    acc[i][j] = __builtin_amdgcn_mfma_f32_16x16x32_bf16(bfr[j], af[i], acc[i][j], 0, 0, 0);
                else
                    acc[i][j] = __builtin_amdgcn_mfma_f32_16x16x32_bf16(af[i], bfr[j], acc[i][j], 0, 0, 0);
            }
    };

    // K = 32 tiles of 32. A tri-buffer pipeline, counted vmcnt; B in regs.
    STAGE(0, 0);
    STAGE(1, 1);
    asm volatile("s_waitcnt vmcnt(2)" ::: "memory");   // A(0) landed; A(1) in flight
    __builtin_amdgcn_sched_barrier(0);
    for (int kt = 0; kt < 32; ++kt) {
        __builtin_amdgcn_s_barrier();      // A(kt) published (forced last iter)
        __builtin_amdgcn_sched_barrier(0);
        bf16x8 bfr[4];
#pragma unroll
        for (int j = 0; j < 4; ++j)
            bfr[j] = *(const bf16x8*)(gBf[j] + kt * 32);
        if (kt + 2 < 32) STAGE((kt + 2) % 3, kt + 2);
        __builtin_amdgcn_sched_barrier(0);
        if (kt < 30) {
            asm volatile("s_waitcnt vmcnt(2)" ::: "memory"); // loadB(kt)+A(kt+1) done
        } else {
            asm volatile("s_waitcnt vmcnt(0)" ::: "memory"); // tail drain
        }
        __builtin_amdgcn_sched_barrier(0);
        __builtin_amdgcn_s_setprio(1);
        COMPUTE(kt % 3, bfr);
        __builtin_amdgcn_s_setprio(0);
    }

    if constexpr (OUT_MODE == 2) {
        const int b = m0 >> 11;
        unsigned short* VT = (unsigned short*)Cout;
#pragma unroll
        for (int i = 0; i < 4; ++i) {
#pragma unroll
            for (int j = 0; j < 4; ++j) {
#pragma unroll
                for (int r = 0; r < 4; ++r) {
                    int d = n0 + wcol + j * 16 + quad * 4 + r;
                    int tok = (m0 & 2047) + wrow + i * 16 + lr;
                    float val = acc[i][j][r] + bias[d];
                    int t6 = tok & 63;
                    int ntok = (tok & ~63) | ((((t6 >> 3) ^ (d & 7)) << 3)) | (t6 & 7);
                    VT[(((size_t)b * 16 + (d >> 6)) * 64 + (d & 63)) * 2048 + ntok] = f2bf(val);
                }
            }
        }
    } else if constexpr (OUT_MODE == 3) {
        unsigned short* C = (unsigned short*)Cout;
#pragma unroll
        for (int i = 0; i < 4; ++i) {
#pragma unroll
            for (int j = 0; j < 4; ++j) {
#pragma unroll
                for (int r = 0; r < 4; ++r) {
                    int row = m0 + wrow + i * 16 + quad * 4 + r;
                    int col = n0 + wcol + j * 16 + lr;
                    float val = acc[i][j][r] + bias[col];
                    int r6 = row & 63;
                    int srow = (r6 & 32) | (((r6 >> 2) & 1) << 4) |
                               (((r6 >> 3) & 3) << 2) | (r6 & 3);
                    int nrow = (row & ~63) | srow;
                    int c6 = col & 63;
                    int ncol = (col & ~63) | ((((c6 >> 3) ^ (srow & 7)) << 3)) | (c6 & 7);
                    C[(size_t)nrow * N + ncol] = f2bf(val);
                }
            }
        }
    } else if constexpr (OUT_MODE == 1) {
        unsigned short* C = (unsigned short*)Cout;
#pragma unroll
        for (int i = 0; i < 4; ++i) {
#pragma unroll
            for (int j = 0; j < 4; ++j) {
#pragma unroll
                for (int r = 0; r < 4; ++r) {
                    int row = m0 + wrow + i * 16 + quad * 4 + r;
                    int col = n0 + wcol + j * 16 + lr;
                    float val = (acc[i][j][r] + bias[col]) * scale;
                    C[(size_t)row * N + col] = f2bf(val);
                }
            }
        }
    } else {
#pragma unroll
        for (int i = 0; i < 4; ++i) {
#pragma unroll
            for (int j = 0; j < 4; ++j) {
#pragma unroll
                for (int r = 0; r < 4; ++r) {
                    int row = m0 + wrow + i * 16 + quad * 4 + r;
                    int col = n0 + wcol + j * 16 + lr;
                    ((float*)Cout)[(size_t)row * N + col] = acc[i][j][r] + bias[col];
                }
            }
        }
    }
}

// XCD-bijective swizzle for 256-block slices (32 m-tiles x 8 n-tiles)
__device__ __forceinline__ void gemm_swz256(int bx, int& m0, int& n0) {
    const int wid = (bx & 7) * 32 + (bx >> 3);  // bijective (256 % 8 == 0)
    m0 = (wid >> 3) * 256;
    n0 = (wid & 7) * 128;
}

// Fused Q+K+V projections, one dispatch. grid (256, 1, 3), 512 threads.
// Safe only when qb does NOT alias Kp (big-ws path).
__global__ __launch_bounds__(512, 4) void gemm_qkv3(
    const unsigned short* __restrict__ qb, const unsigned short* __restrict__ wqb,
    const float* __restrict__ bq, unsigned short* __restrict__ Qp,
    const unsigned short* __restrict__ kb, const unsigned short* __restrict__ wkb,
    const float* __restrict__ bk, unsigned short* __restrict__ Kp,
    const unsigned short* __restrict__ vb, const unsigned short* __restrict__ wvb,
    const float* __restrict__ bv, unsigned short* __restrict__ VTp, float qscale) {
    __shared__ unsigned short lds[3 * 8192];
    int m0, n0;
    gemm_swz256(blockIdx.x, m0, n0);
    if (blockIdx.z == 0)
        gemm256_body<1>(qb, wqb, bq, Qp, lds, m0, n0, qscale);
    else if (blockIdx.z == 1)
        gemm256_body<3>(kb, wkb, bk, Kp, lds, m0, n0, 1.0f);
    else
        gemm256_body<2>(vb, wvb, bv, VTp, lds, m0, n0, 1.0f);
}

// Q projection alone (fallback path). grid (256), 512 threads.
__global__ __launch_bounds__(512, 4) void gemm_q(
    const unsigned short* __restrict__ qb, const unsigned short* __restrict__ wqb,
    const float* __restrict__ bq, unsigned short* __restrict__ Qp, float qscale) {
    __shared__ unsigned short lds[3 * 8192];
    int m0, n0;
    gemm_swz256(blockIdx.x, m0, n0);
    gemm256_body<1>(qb, wqb, bq, Qp, lds, m0, n0, qscale);
}

// K and V projections (fallback path). grid (256, 1, 2), 512 threads.
__global__ __launch_bounds__(512, 4) void gemm_kv(
    const unsigned short* __restrict__ kb, const unsigned short* __restrict__ wkb,
    const float* __restrict__ bk, unsigned short* __restrict__ Kp,
    const unsigned short* __restrict__ vb, const unsigned short* __restrict__ wvb,
    const float* __restrict__ bv, unsigned short* __restrict__ VTp) {
    __shared__ unsigned short lds[3 * 8192];
    int m0, n0;
    gemm_swz256(blockIdx.x, m0, n0);
    if (blockIdx.z == 0)
        gemm256_body<3>(kb, wkb, bk, Kp, lds, m0, n0, 1.0f);
    else
        gemm256_body<2>(vb, wvb, bv, VTp, lds, m0, n0, 1.0f);
}

// O projection. grid (256), 512 threads.
__global__ __launch_bounds__(512, 4) void gemm_o(const unsigned short* __restrict__ A,
                                                 const unsigned short* __restrict__ W,
                                                 const float* __restrict__ bias,
                                                 void* __restrict__ C) {
    __shared__ unsigned short lds[3 * 8192];
    int m0, n0;
    gemm_swz256(blockIdx.x, m0, n0);
    gemm256_body<0>(A, W, bias, C, lds, m0, n0, 1.0f);
}

// Flash attention v4 (verified): 64 q per wave (QBLK=256). K/V pre-permuted +
// XOR-swizzled in GLOBAL memory; bare global_load_lds staging, dbuf, 1 barrier
// per 64-key tile. grid (8 q-tiles, 16 h, 4 b), 256 thr = 4 waves, 64 q/wave.
__global__ __launch_bounds__(256, 2) void attn_kernel(const unsigned short* __restrict__ Qp,
                                                      const unsigned short* __restrict__ Kp,
                                                      const unsigned short* __restrict__ VTp,
                                                      unsigned short* __restrict__ Xp) {
    constexpr int L = 2048, D = 1024;
    __shared__ unsigned short Ks[2][64 * 64];   // permuted+swizzled key tiles
    __shared__ unsigned short Vt[2][64 * 64];   // [d][64 keys], swizzled slots

    const int t = threadIdx.x;
    // XCD swizzle: hw linear id -> work id; 512 % 8 == 0 -> bijective.
    const int hw = blockIdx.x + 8 * blockIdx.y + 128 * blockIdx.z;
    const int wid = (hw & 7) * 64 + (hw >> 3);
    const int q0 = (wid & 7) * 256;
    const int h = (wid >> 3) & 15;
    const int b = wid >> 7;
    const int lane = t & 63;
    const int w = t >> 6;
    const int lr = lane & 15;
    const int quad = lane >> 4;
    const int x7 = lr & 7;

    const size_t kbase = ((size_t)(b * L)) * D + (size_t)h * 64;
    const size_t vtbase = ((size_t)(b * 16 + h)) * 64 * 2048;

    auto stage_async = [&](int buf, int kb2) {
        int k0 = kb2 * 64;
#pragma unroll
        for (int i = 0; i < 2; ++i) {
            int idx = t + 256 * i;
            int row = idx >> 3, c16 = idx & 7;
            g2l16(Kp + kbase + (size_t)(k0 + row) * D + c16 * 8,
                  &Ks[buf][(w * 64 + i * 256) * 8]);
            g2l16(VTp + vtbase + (size_t)row * 2048 + k0 + c16 * 8,
                  &Vt[buf][(w * 64 + i * 256) * 8]);
        }
    };

    stage_async(0, 0);   // fire first tile ASAP

    // Q B-frags: B[k=d][n=q], n=lr -> q = q0 + w*64 + qs*16 + lr, qs in 0..3
    const size_t qbase = ((size_t)(b * L + q0)) * D + (size_t)h * 64;
    bf16x8 bq[4][2];
#pragma unroll
    for (int qs = 0; qs < 4; ++qs)
#pragma unroll
        for (int s2 = 0; s2 < 2; ++s2)
            bq[qs][s2] = *(const bf16x8*)(Qp + qbase + (size_t)(w * 64 + qs * 16 + lr) * D +
                                          s2 * 32 + quad * 8);

    floatx4 o[4][4], ol[4];
#pragma unroll
    for (int qs = 0; qs < 4; ++qs) {
        ol[qs] = (floatx4){0.f, 0.f, 0.f, 0.f};
#pragma unroll
        for (int dt = 0; dt < 4; ++dt) o[qs][dt] = (floatx4){0.f, 0.f, 0.f, 0.f};
    }
    bf16x8 ones;
#pragma unroll
    for (int e = 0; e < 8; ++e) ones[e] = (short)0x3F80;

    __syncthreads();     // first tile resident
    int cur = 0;

    // conflict-free slot indices (shorts offset = slot*8)
    const int kc0 = (quad ^ x7) * 8;
    const int kc1 = ((quad + 4) ^ x7) * 8;

    for (int kb = 0; kb < L / 64; ++kb) {
        if (kb < L / 64 - 1) stage_async(cur ^ 1, kb + 1);

        __builtin_amdgcn_s_setprio(1);
#pragma unroll
        for (int g = 0; g < 2; ++g) {
            bf16x8 akA0 = *(const bf16x8*)&Ks[cur][(g * 32 + lr) * 64 + kc0];
            bf16x8 akA1 = *(const bf16x8*)&Ks[cur][(g * 32 + lr) * 64 + kc1];
            bf16x8 akB0 = *(const bf16x8*)&Ks[cur][(g * 32 + 16 + lr) * 64 + kc0];
            bf16x8 akB1 = *(const bf16x8*)&Ks[cur][(g * 32 + 16 + lr) * 64 + kc1];
            bf16x8 vf[4];
#pragma unroll
            for (int dt = 0; dt < 4; ++dt)
                vf[dt] = *(const bf16x8*)&Vt[cur][(dt * 16 + lr) * 64 +
                                                  (((g * 4 + quad) ^ x7) * 8)];

            const floatx4 z4 = (floatx4){0.f, 0.f, 0.f, 0.f};
#pragma unroll
            for (int qs = 0; qs < 4; ++qs) {
                floatx4 stA = __builtin_amdgcn_mfma_f32_16x16x32_bf16(akA0, bq[qs][0], z4, 0, 0, 0);
                stA = __builtin_amdgcn_mfma_f32_16x16x32_bf16(akA1, bq[qs][1], stA, 0, 0, 0);
                floatx4 stB = __builtin_amdgcn_mfma_f32_16x16x32_bf16(akB0, bq[qs][0], z4, 0, 0, 0);
                stB = __builtin_amdgcn_mfma_f32_16x16x32_bf16(akB1, bq[qs][1], stB, 0, 0, 0);

                // exp(S^T) packed as K=32 A-frag: lane m=q(lr), k = quad*8 + j
                union { unsigned int u[4]; bf16x8 v; } pf;
                pf.u[0] = pack2bf_t(EXP2F(stA[0]), EXP2F(stA[1]));
                pf.u[1] = pack2bf_t(EXP2F(stA[2]), EXP2F(stA[3]));
                pf.u[2] = pack2bf_t(EXP2F(stB[0]), EXP2F(stB[1]));
                pf.u[3] = pack2bf_t(EXP2F(stB[2]), EXP2F(stB[3]));

                ol[qs] = __builtin_amdgcn_mfma_f32_16x16x32_bf16(pf.v, ones, ol[qs], 0, 0, 0);
#pragma unroll
                for (int dt = 0; dt < 4; ++dt)
                    o[qs][dt] = __builtin_amdgcn_mfma_f32_16x16x32_bf16(pf.v, vf[dt],
                                                                        o[qs][dt], 0, 0, 0);
            }
        }
        __builtin_amdgcn_s_setprio(0);

        if (kb < L / 64 - 1) {
            __syncthreads();   // drains this wave's g2l (vmcnt) + joins block
            cur ^= 1;
        }
    }

    // epilogue: D[m=q][n=d]: q = q0 + w*64 + qs*16 + quad*4 + r, d = dt*16 + lr
#pragma unroll
    for (int qs = 0; qs < 4; ++qs) {
#pragma unroll
        for (int r = 0; r < 4; ++r) {
            float inv = 1.0f / ol[qs][r];
            int q = q0 + w * 64 + qs * 16 + quad * 4 + r;
            size_t base = ((size_t)(b * L + q)) * D + (size_t)h * 64;
#pragma unroll
            for (int dt = 0; dt < 4; ++dt)
                Xp[base + dt * 16 + lr] = f2bf(o[qs][dt][r] * inv);
        }
    }
}

extern "C" void kernel_launch(void* const* d_in, const int* in_sizes, int n_in,
                              void* d_out, int out_size, void* d_ws, size_t ws_size,
                              hipStream_t stream) {
    const float* query = (const float*)d_in[0];
    const float* key_  = (const float*)d_in[1];
    const float* value = (const float*)d_in[2];
    const float* Wq = (const float*)d_in[3];
    const float* bq = (const float*)d_in[4];
    const float* Wk = (const float*)d_in[5];
    const float* bk = (const float*)d_in[6];
    const float* Wv = (const float*)d_in[7];
    const float* bv = (const float*)d_in[8];
    const float* Wo = (const float*)d_in[9];
    const float* bo = (const float*)d_in[10];
    float* out = (float*)d_out;

    const size_t MB16 = (size_t)8 * 1024 * 1024;   // 16 MB in ushort units

    // ws base (64 MB): [0:16) Qp | [16:32) kb->Xp | [32:48) vb | [48:64) VTp
    unsigned short* Qp  = (unsigned short*)d_ws;
    unsigned short* kb  = Qp + MB16;
    unsigned short* vb  = kb + MB16;
    unsigned short* VTp = vb + MB16;
    unsigned short* Xp  = kb;
    // d_out scratch: [0:16) Kp | [16:22) wqb,wkb,wvb  (gemm_o overwrites later)
    unsigned short* Kp  = (unsigned short*)d_out;
    unsigned short* wqb = Kp + MB16;
    unsigned short* wkb = wqb + 1024 * 1024;
    unsigned short* wvb = wkb + 1024 * 1024;

    const float qscale = 0.125f * 1.44269504f;
    dim3 bb(256);

    const bool bigws = ws_size >= (size_t)82 * 1024 * 1024;

    if (bigws) {
        // qb at ws+64MB, wob at ws+80MB: no aliasing -> Q/K/V in ONE dispatch
        // and Wo conversion fused into cvt. 4 launches total.
        unsigned short* qb  = VTp + MB16;            // ws[64:80)
        unsigned short* wob = qb + MB16;             // ws[80:82)
        cvt_kernel<<<dim3(24576 + 4096), bb, 0, stream>>>(query, key_, value, Wq, Wk, Wv, Wo,
                                                          qb, kb, vb, wqb, wkb, wvb, wob);
        gemm_qkv3<<<dim3(256, 1, 3), dim3(512), 0, stream>>>(qb, wqb, bq, Qp,
                                                             kb, wkb, bk, Kp,
                                                             vb, wvb, bv, VTp, qscale);
        attn_kernel<<<dim3(8, 16, 4), bb, 0, stream>>>(Qp, Kp, VTp, Xp);
        gemm_o<<<dim3(256), dim3(512), 0, stream>>>(Xp, wob, bo, out);
    } else {
        // Fallback (verified flow): qb aliases Kp (stream-serialized),
        // wob aliases vb (written after gemm_kv consumed vb). 6 launches.
        unsigned short* qb  = (unsigned short*)d_out;
        unsigned short* wob = vb;
        cvt_kernel<<<dim3(24576 + 3072), bb, 0, stream>>>(query, key_, value, Wq, Wk, Wv, Wo,
                                                          qb, kb, vb, wqb, wkb, wvb, nullptr);
        gemm_q<<<dim3(256), dim3(512), 0, stream>>>(qb, wqb, bq, Qp, qscale);
        gemm_kv<<<dim3(256, 1, 2), dim3(512), 0, stream>>>(kb, wkb, bk, Kp,
                                                           vb, wvb, bv, VTp);
        attn_kernel<<<dim3(8, 16, 4), bb, 0, stream>>>(Qp, Kp, VTp, Xp);
        cvt1_kernel<<<dim3(1024), bb, 0, stream>>>(Wo, wob);
        gemm_o<<<dim3(256), dim3(512), 0, stream>>>(Xp, wob, bo, out);
    }
}

// Round 13
// 383.237 us; speedup vs baseline: 1.0186x; 1.0186x over previous
//
#include <hip/hip_runtime.h>

typedef float floatx4 __attribute__((ext_vector_type(4)));
typedef short bf16x8 __attribute__((ext_vector_type(8)));
typedef const unsigned int __attribute__((address_space(1))) gas_u32;
typedef unsigned int __attribute__((address_space(3))) las_u32;

#if __has_builtin(__builtin_amdgcn_exp2f)
#define EXP2F(x) __builtin_amdgcn_exp2f(x)
#else
#define EXP2F(x) exp2f(x)
#endif

__device__ __forceinline__ unsigned short f2bf(float x) {
    unsigned int u = __float_as_uint(x);
    unsigned int r = u + 0x7fffu + ((u >> 16) & 1u);
    return (unsigned short)(r >> 16);
}

// truncating pack (P>=0; downward bias cancels in O/l ratio).
__device__ __forceinline__ unsigned int pack2bf_t(float lo, float hi) {
#if __has_builtin(__builtin_amdgcn_perm)
    return __builtin_amdgcn_perm(__float_as_uint(hi), __float_as_uint(lo), 0x07060302u);
#else
    return (__float_as_uint(lo) >> 16) | (__float_as_uint(hi) & 0xffff0000u);
#endif
}

__device__ __forceinline__ void g2l16(const void* g, void* l) {
    __builtin_amdgcn_global_load_lds((gas_u32*)(unsigned long long)g,
                                     (las_u32*)(unsigned int)(unsigned long long)l,
                                     16, 0, 0);
}

// fp32 -> bf16, exact-size linear grid (no idle blocks).
__global__ __launch_bounds__(256) void cvt_kernel(
    const float* __restrict__ q, const float* __restrict__ k, const float* __restrict__ v,
    const float* __restrict__ wq, const float* __restrict__ wk, const float* __restrict__ wv,
    const float* __restrict__ wo,
    unsigned short* __restrict__ qb, unsigned short* __restrict__ kb,
    unsigned short* __restrict__ vb, unsigned short* __restrict__ wqb,
    unsigned short* __restrict__ wkb, unsigned short* __restrict__ wvb,
    unsigned short* __restrict__ wob) {
    const int bid = blockIdx.x;
    const float* src;
    unsigned short* dst;
    int off;
    if (bid < 24576) {
        int s = bid >> 13;                       // 0..2
        off = (bid & 8191) * 256 + threadIdx.x;  // < 2097152 exact
        src = (s == 0) ? q : (s == 1) ? k : v;
        dst = (s == 0) ? qb : (s == 1) ? kb : vb;
    } else {
        int r = bid - 24576;
        int s = r >> 10;                         // 0..3
        off = (r & 1023) * 256 + threadIdx.x;    // < 262144 exact
        src = (s == 0) ? wq : (s == 1) ? wk : (s == 2) ? wv : wo;
        dst = (s == 0) ? wqb : (s == 1) ? wkb : (s == 2) ? wvb : wob;
    }
    float4 x = ((const float4*)src)[off];
    ushort4 o;
    o.x = f2bf(x.x); o.y = f2bf(x.y); o.z = f2bf(x.z); o.w = f2bf(x.w);
    ((ushort4*)dst)[off] = o;
}

// Wo fp32 -> bf16 (1M floats). grid 1024. Fallback (small-ws) path only.
__global__ __launch_bounds__(256) void cvt1_kernel(const float* __restrict__ wo,
                                                   unsigned short* __restrict__ wob) {
    int i = blockIdx.x * 256 + threadIdx.x;
    float4 x = ((const float4*)wo)[i];
    ushort4 o;
    o.x = f2bf(x.x); o.y = f2bf(x.y); o.z = f2bf(x.z); o.w = f2bf(x.w);
    ((ushort4*)wob)[i] = o;
}

// -------- 256x128 tile, BK=32, 512 threads (8 waves, 4M x 2N) --------------
// v4: B operand direct L2->reg, DOUBLE-BUFFERED one iteration ahead (fixes
// R12's exposed-latency regression: loadB(kt+1) issues after barrier(kt) and
// is consumed at kt+1, hiding ~300cy L2 latency under COMPUTE(kt)).
// A via tri-buffered g2l LDS (48 KB -> 2 blocks/CU), T2 XOR-swizzled.
// Loop unrolled x2 so B reg buffers are statically named (no scratch).
// Wait accounting at iter kt (queue oldest->newest: A(kt)x2, B(kt)x4,
// A(kt+1)x2): manual vmcnt(6) forces own A(kt) before the barrier (publish
// invariant, as verified in R11); compiler's reg-dependency wait handles
// B(kt), issued a full iteration earlier. Tail (kt>=30) drains vmcnt(0).
// OUT_MODE: 0 = fp32 out, 1 = bf16 out scaled,
//           2 = VT transpose (swizzled), 3 = K permuted (swizzled).
template <int OUT_MODE>
__device__ __forceinline__ void gemm256_body(const unsigned short* __restrict__ Asrc,
                                             const unsigned short* __restrict__ W,
                                             const float* __restrict__ bias,
                                             void* __restrict__ Cout,
                                             unsigned short* lds, int m0, int n0,
                                             float scale) {
    constexpr int K = 1024, N = 1024;
    constexpr int BUFS = 256 * 32;          // A-only buffer: 8192 shorts = 16 KB
    const int t = threadIdx.x;
    const int lane = t & 63, w = t >> 6;
    const int lr = lane & 15, quad = lane >> 4;
    const int wrow = (w & 3) * 64, wcol = (w >> 2) * 64;

    // A staging sources: 4 x 16B slots per row (BK=32); source-col pre-swizzled
    // with key (row>>1)&3 so linear LDS dest + XOR'd read is conflict-free.
    const unsigned short* gA[2];
#pragma unroll
    for (int i = 0; i < 2; ++i) {
        int idx = t + 512 * i;          // 0..1023 -> 256 rows x 4 slots
        int row = idx >> 2, sl = idx & 3;
        gA[i] = Asrc + (size_t)(m0 + row) * K + ((sl ^ ((row >> 1) & 3)) * 8);
    }
    // B fragment pointers: direct global (natural layout, no swizzle).
    const unsigned short* gBf[4];
#pragma unroll
    for (int j = 0; j < 4; ++j)
        gBf[j] = W + (size_t)(n0 + wcol + j * 16 + lr) * K + quad * 8;

    auto STAGE = [&](int buf, int kt) {     // 2 g2l per thread per stage
        unsigned short* dst = lds + buf * BUFS;
#pragma unroll
        for (int i = 0; i < 2; ++i)
            g2l16(gA[i] + kt * 32, dst + (w * 64 + i * 512) * 8);
    };

    auto LOADB = [&](bf16x8 (&dst)[4], int kt) {
#pragma unroll
        for (int j = 0; j < 4; ++j)
            dst[j] = *(const bf16x8*)(gBf[j] + kt * 32);
    };

    floatx4 acc[4][4];
#pragma unroll
    for (int i = 0; i < 4; ++i)
#pragma unroll
        for (int j = 0; j < 4; ++j) acc[i][j] = (floatx4){0.f, 0.f, 0.f, 0.f};

    const int sc = (quad ^ ((lr >> 1) & 3)) * 8;   // A read slot (XOR involution)

    auto COMPUTE = [&](int buf, const bf16x8 (&bfr)[4]) {
        const unsigned short* Ab = lds + buf * BUFS;
        bf16x8 af[4];
#pragma unroll
        for (int i = 0; i < 4; ++i)
            af[i] = *(const bf16x8*)&Ab[(wrow + i * 16 + lr) * 32 + sc];
#pragma unroll
        for (int i = 0; i < 4; ++i)
#pragma unroll
            for (int j = 0; j < 4; ++j) {
                if constexpr (OUT_MODE == 2)
                    acc[i][j] = __builtin_amdgcn_mfma_f32_16x16x32_bf16(bfr[j], af[i], acc[i][j], 0, 0, 0);
                else
                    acc[i][j] = __builtin_amdgcn_mfma_f32_16x16x32_bf16(af[i], bfr[j], acc[i][j], 0, 0, 0);
            }
    };

    bf16x8 bA[4], bB[4];

    // K = 32 tiles of 32. A tri-buffer (g2l) + B reg double-buffer.
    STAGE(0, 0);
    STAGE(1, 1);
    LOADB(bA, 0);
    for (int kt2 = 0; kt2 < 32; kt2 += 2) {
        // ---- even step: kt = kt2, consume bA, prefetch bB = B(kt+1) ----
        if (kt2 < 30) {
            asm volatile("s_waitcnt vmcnt(6)" ::: "memory");  // own A(kt) done
        } else {
            asm volatile("s_waitcnt vmcnt(0)" ::: "memory");
        }
        __builtin_amdgcn_sched_barrier(0);
        __builtin_amdgcn_s_barrier();      // A(kt) published by all waves
        __builtin_amdgcn_sched_barrier(0);
        LOADB(bB, kt2 + 1);
        if (kt2 + 2 < 32) STAGE((kt2 + 2) % 3, kt2 + 2);
        __builtin_amdgcn_sched_barrier(0);
        __builtin_amdgcn_s_setprio(1);
        COMPUTE(kt2 % 3, bA);
        __builtin_amdgcn_s_setprio(0);

        // ---- odd step: kt = kt2+1, consume bB, prefetch bA = B(kt+1) ----
        if (kt2 + 1 < 30) {
            asm volatile("s_waitcnt vmcnt(6)" ::: "memory");  // own A(kt) done
        } else {
            asm volatile("s_waitcnt vmcnt(0)" ::: "memory");
        }
        __builtin_amdgcn_sched_barrier(0);
        __builtin_amdgcn_s_barrier();
        __builtin_amdgcn_sched_barrier(0);
        if (kt2 + 2 < 32) LOADB(bA, kt2 + 2);
        if (kt2 + 3 < 32) STAGE((kt2 + 3) % 3, kt2 + 3);
        __builtin_amdgcn_sched_barrier(0);
        __builtin_amdgcn_s_setprio(1);
        COMPUTE((kt2 + 1) % 3, bB);
        __builtin_amdgcn_s_setprio(0);
    }

    if constexpr (OUT_MODE == 2) {
        const int b = m0 >> 11;
        unsigned short* VT = (unsigned short*)Cout;
#pragma unroll
        for (int i = 0; i < 4; ++i) {
#pragma unroll
            for (int j = 0; j < 4; ++j) {
#pragma unroll
                for (int r = 0; r < 4; ++r) {
                    int d = n0 + wcol + j * 16 + quad * 4 + r;
                    int tok = (m0 & 2047) + wrow + i * 16 + lr;
                    float val = acc[i][j][r] + bias[d];
                    int t6 = tok & 63;
                    int ntok = (tok & ~63) | ((((t6 >> 3) ^ (d & 7)) << 3)) | (t6 & 7);
                    VT[(((size_t)b * 16 + (d >> 6)) * 64 + (d & 63)) * 2048 + ntok] = f2bf(val);
                }
            }
        }
    } else if constexpr (OUT_MODE == 3) {
        unsigned short* C = (unsigned short*)Cout;
#pragma unroll
        for (int i = 0; i < 4; ++i) {
#pragma unroll
            for (int j = 0; j < 4; ++j) {
#pragma unroll
                for (int r = 0; r < 4; ++r) {
                    int row = m0 + wrow + i * 16 + quad * 4 + r;
                    int col = n0 + wcol + j * 16 + lr;
                    float val = acc[i][j][r] + bias[col];
                    int r6 = row & 63;
                    int srow = (r6 & 32) | (((r6 >> 2) & 1) << 4) |
                               (((r6 >> 3) & 3) << 2) | (r6 & 3);
                    int nrow = (row & ~63) | srow;
                    int c6 = col & 63;
                    int ncol = (col & ~63) | ((((c6 >> 3) ^ (srow & 7)) << 3)) | (c6 & 7);
                    C[(size_t)nrow * N + ncol] = f2bf(val);
                }
            }
        }
    } else if constexpr (OUT_MODE == 1) {
        unsigned short* C = (unsigned short*)Cout;
#pragma unroll
        for (int i = 0; i < 4; ++i) {
#pragma unroll
            for (int j = 0; j < 4; ++j) {
#pragma unroll
                for (int r = 0; r < 4; ++r) {
                    int row = m0 + wrow + i * 16 + quad * 4 + r;
                    int col = n0 + wcol + j * 16 + lr;
                    float val = (acc[i][j][r] + bias[col]) * scale;
                    C[(size_t)row * N + col] = f2bf(val);
                }
            }
        }
    } else {
#pragma unroll
        for (int i = 0; i < 4; ++i) {
#pragma unroll
            for (int j = 0; j < 4; ++j) {
#pragma unroll
                for (int r = 0; r < 4; ++r) {
                    int row = m0 + wrow + i * 16 + quad * 4 + r;
                    int col = n0 + wcol + j * 16 + lr;
                    ((float*)Cout)[(size_t)row * N + col] = acc[i][j][r] + bias[col];
                }
            }
        }
    }
}

// XCD-bijective swizzle for 256-block slices (32 m-tiles x 8 n-tiles)
__device__ __forceinline__ void gemm_swz256(int bx, int& m0, int& n0) {
    const int wid = (bx & 7) * 32 + (bx >> 3);  // bijective (256 % 8 == 0)
    m0 = (wid >> 3) * 256;
    n0 = (wid & 7) * 128;
}

// Fused Q+K+V projections, one dispatch. grid (256, 1, 3), 512 threads.
// Safe only when qb does NOT alias Kp (big-ws path).
__global__ __launch_bounds__(512, 4) void gemm_qkv3(
    const unsigned short* __restrict__ qb, const unsigned short* __restrict__ wqb,
    const float* __restrict__ bq, unsigned short* __restrict__ Qp,
    const unsigned short* __restrict__ kb, const unsigned short* __restrict__ wkb,
    const float* __restrict__ bk, unsigned short* __restrict__ Kp,
    const unsigned short* __restrict__ vb, const unsigned short* __restrict__ wvb,
    const float* __restrict__ bv, unsigned short* __restrict__ VTp, float qscale) {
    __shared__ unsigned short lds[3 * 8192];
    int m0, n0;
    gemm_swz256(blockIdx.x, m0, n0);
    if (blockIdx.z == 0)
        gemm256_body<1>(qb, wqb, bq, Qp, lds, m0, n0, qscale);
    else if (blockIdx.z == 1)
        gemm256_body<3>(kb, wkb, bk, Kp, lds, m0, n0, 1.0f);
    else
        gemm256_body<2>(vb, wvb, bv, VTp, lds, m0, n0, 1.0f);
}

// Q projection alone (fallback path). grid (256), 512 threads.
__global__ __launch_bounds__(512, 4) void gemm_q(
    const unsigned short* __restrict__ qb, const unsigned short* __restrict__ wqb,
    const float* __restrict__ bq, unsigned short* __restrict__ Qp, float qscale) {
    __shared__ unsigned short lds[3 * 8192];
    int m0, n0;
    gemm_swz256(blockIdx.x, m0, n0);
    gemm256_body<1>(qb, wqb, bq, Qp, lds, m0, n0, qscale);
}

// K and V projections (fallback path). grid (256, 1, 2), 512 threads.
__global__ __launch_bounds__(512, 4) void gemm_kv(
    const unsigned short* __restrict__ kb, const unsigned short* __restrict__ wkb,
    const float* __restrict__ bk, unsigned short* __restrict__ Kp,
    const unsigned short* __restrict__ vb, const unsigned short* __restrict__ wvb,
    const float* __restrict__ bv, unsigned short* __restrict__ VTp) {
    __shared__ unsigned short lds[3 * 8192];
    int m0, n0;
    gemm_swz256(blockIdx.x, m0, n0);
    if (blockIdx.z == 0)
        gemm256_body<3>(kb, wkb, bk, Kp, lds, m0, n0, 1.0f);
    else
        gemm256_body<2>(vb, wvb, bv, VTp, lds, m0, n0, 1.0f);
}

// O projection. grid (256), 512 threads.
__global__ __launch_bounds__(512, 4) void gemm_o(const unsigned short* __restrict__ A,
                                                 const unsigned short* __restrict__ W,
                                                 const float* __restrict__ bias,
                                                 void* __restrict__ C) {
    __shared__ unsigned short lds[3 * 8192];
    int m0, n0;
    gemm_swz256(blockIdx.x, m0, n0);
    gemm256_body<0>(A, W, bias, C, lds, m0, n0, 1.0f);
}

// Flash attention v4 (verified): 64 q per wave (QBLK=256). K/V pre-permuted +
// XOR-swizzled in GLOBAL memory; bare global_load_lds staging, dbuf, 1 barrier
// per 64-key tile. grid (8 q-tiles, 16 h, 4 b), 256 thr = 4 waves, 64 q/wave.
__global__ __launch_bounds__(256, 2) void attn_kernel(const unsigned short* __restrict__ Qp,
                                                      const unsigned short* __restrict__ Kp,
                                                      const unsigned short* __restrict__ VTp,
                                                      unsigned short* __restrict__ Xp) {
    constexpr int L = 2048, D = 1024;
    __shared__ unsigned short Ks[2][64 * 64];   // permuted+swizzled key tiles
    __shared__ unsigned short Vt[2][64 * 64];   // [d][64 keys], swizzled slots

    const int t = threadIdx.x;
    // XCD swizzle: hw linear id -> work id; 512 % 8 == 0 -> bijective.
    const int hw = blockIdx.x + 8 * blockIdx.y + 128 * blockIdx.z;
    const int wid = (hw & 7) * 64 + (hw >> 3);
    const int q0 = (wid & 7) * 256;
    const int h = (wid >> 3) & 15;
    const int b = wid >> 7;
    const int lane = t & 63;
    const int w = t >> 6;
    const int lr = lane & 15;
    const int quad = lane >> 4;
    const int x7 = lr & 7;

    const size_t kbase = ((size_t)(b * L)) * D + (size_t)h * 64;
    const size_t vtbase = ((size_t)(b * 16 + h)) * 64 * 2048;

    auto stage_async = [&](int buf, int kb2) {
        int k0 = kb2 * 64;
#pragma unroll
        for (int i = 0; i < 2; ++i) {
            int idx = t + 256 * i;
            int row = idx >> 3, c16 = idx & 7;
            g2l16(Kp + kbase + (size_t)(k0 + row) * D + c16 * 8,
                  &Ks[buf][(w * 64 + i * 256) * 8]);
            g2l16(VTp + vtbase + (size_t)row * 2048 + k0 + c16 * 8,
                  &Vt[buf][(w * 64 + i * 256) * 8]);
        }
    };

    stage_async(0, 0);   // fire first tile ASAP

    // Q B-frags: B[k=d][n=q], n=lr -> q = q0 + w*64 + qs*16 + lr, qs in 0..3
    const size_t qbase = ((size_t)(b * L + q0)) * D + (size_t)h * 64;
    bf16x8 bq[4][2];
#pragma unroll
    for (int qs = 0; qs < 4; ++qs)
#pragma unroll
        for (int s2 = 0; s2 < 2; ++s2)
            bq[qs][s2] = *(const bf16x8*)(Qp + qbase + (size_t)(w * 64 + qs * 16 + lr) * D +
                                          s2 * 32 + quad * 8);

    floatx4 o[4][4], ol[4];
#pragma unroll
    for (int qs = 0; qs < 4; ++qs) {
        ol[qs] = (floatx4){0.f, 0.f, 0.f, 0.f};
#pragma unroll
        for (int dt = 0; dt < 4; ++dt) o[qs][dt] = (floatx4){0.f, 0.f, 0.f, 0.f};
    }
    bf16x8 ones;
#pragma unroll
    for (int e = 0; e < 8; ++e) ones[e] = (short)0x3F80;

    __syncthreads();     // first tile resident
    int cur = 0;

    // conflict-free slot indices (shorts offset = slot*8)
    const int kc0 = (quad ^ x7) * 8;
    const int kc1 = ((quad + 4) ^ x7) * 8;

    for (int kb = 0; kb < L / 64; ++kb) {
        if (kb < L / 64 - 1) stage_async(cur ^ 1, kb + 1);

        __builtin_amdgcn_s_setprio(1);
#pragma unroll
        for (int g = 0; g < 2; ++g) {
            bf16x8 akA0 = *(const bf16x8*)&Ks[cur][(g * 32 + lr) * 64 + kc0];
            bf16x8 akA1 = *(const bf16x8*)&Ks[cur][(g * 32 + lr) * 64 + kc1];
            bf16x8 akB0 = *(const bf16x8*)&Ks[cur][(g * 32 + 16 + lr) * 64 + kc0];
            bf16x8 akB1 = *(const bf16x8*)&Ks[cur][(g * 32 + 16 + lr) * 64 + kc1];
            bf16x8 vf[4];
#pragma unroll
            for (int dt = 0; dt < 4; ++dt)
                vf[dt] = *(const bf16x8*)&Vt[cur][(dt * 16 + lr) * 64 +
                                                  (((g * 4 + quad) ^ x7) * 8)];

            const floatx4 z4 = (floatx4){0.f, 0.f, 0.f, 0.f};
#pragma unroll
            for (int qs = 0; qs < 4; ++qs) {
                floatx4 stA = __builtin_amdgcn_mfma_f32_16x16x32_bf16(akA0, bq[qs][0], z4, 0, 0, 0);
                stA = __builtin_amdgcn_mfma_f32_16x16x32_bf16(akA1, bq[qs][1], stA, 0, 0, 0);
                floatx4 stB = __builtin_amdgcn_mfma_f32_16x16x32_bf16(akB0, bq[qs][0], z4, 0, 0, 0);
                stB = __builtin_amdgcn_mfma_f32_16x16x32_bf16(akB1, bq[qs][1], stB, 0, 0, 0);

                // exp(S^T) packed as K=32 A-frag: lane m=q(lr), k = quad*8 + j
                union { unsigned int u[4]; bf16x8 v; } pf;
                pf.u[0] = pack2bf_t(EXP2F(stA[0]), EXP2F(stA[1]));
                pf.u[1] = pack2bf_t(EXP2F(stA[2]), EXP2F(stA[3]));
                pf.u[2] = pack2bf_t(EXP2F(stB[0]), EXP2F(stB[1]));
                pf.u[3] = pack2bf_t(EXP2F(stB[2]), EXP2F(stB[3]));

                ol[qs] = __builtin_amdgcn_mfma_f32_16x16x32_bf16(pf.v, ones, ol[qs], 0, 0, 0);
#pragma unroll
                for (int dt = 0; dt < 4; ++dt)
                    o[qs][dt] = __builtin_amdgcn_mfma_f32_16x16x32_bf16(pf.v, vf[dt],
                                                                        o[qs][dt], 0, 0, 0);
            }
        }
        __builtin_amdgcn_s_setprio(0);

        if (kb < L / 64 - 1) {
            __syncthreads();   // drains this wave's g2l (vmcnt) + joins block
            cur ^= 1;
        }
    }

    // epilogue: D[m=q][n=d]: q = q0 + w*64 + qs*16 + quad*4 + r, d = dt*16 + lr
#pragma unroll
    for (int qs = 0; qs < 4; ++qs) {
#pragma unroll
        for (int r = 0; r < 4; ++r) {
            float inv = 1.0f / ol[qs][r];
            int q = q0 + w * 64 + qs * 16 + quad * 4 + r;
            size_t base = ((size_t)(b * L + q)) * D + (size_t)h * 64;
#pragma unroll
            for (int dt = 0; dt < 4; ++dt)
                Xp[base + dt * 16 + lr] = f2bf(o[qs][dt][r] * inv);
        }
    }
}

extern "C" void kernel_launch(void* const* d_in, const int* in_sizes, int n_in,
                              void* d_out, int out_size, void* d_ws, size_t ws_size,
                              hipStream_t stream) {
    const float* query = (const float*)d_in[0];
    const float* key_  = (const float*)d_in[1];
    const float* value = (const float*)d_in[2];
    const float* Wq = (const float*)d_in[3];
    const float* bq = (const float*)d_in[4];
    const float* Wk = (const float*)d_in[5];
    const float* bk = (const float*)d_in[6];
    const float* Wv = (const float*)d_in[7];
    const float* bv = (const float*)d_in[8];
    const float* Wo = (const float*)d_in[9];
    const float* bo = (const float*)d_in[10];
    float* out = (float*)d_out;

    const size_t MB16 = (size_t)8 * 1024 * 1024;   // 16 MB in ushort units

    // ws base (64 MB): [0:16) Qp | [16:32) kb->Xp | [32:48) vb | [48:64) VTp
    unsigned short* Qp  = (unsigned short*)d_ws;
    unsigned short* kb  = Qp + MB16;
    unsigned short* vb  = kb + MB16;
    unsigned short* VTp = vb + MB16;
    unsigned short* Xp  = kb;
    // d_out scratch: [0:16) Kp | [16:22) wqb,wkb,wvb  (gemm_o overwrites later)
    unsigned short* Kp  = (unsigned short*)d_out;
    unsigned short* wqb = Kp + MB16;
    unsigned short* wkb = wqb + 1024 * 1024;
    unsigned short* wvb = wkb + 1024 * 1024;

    const float qscale = 0.125f * 1.44269504f;
    dim3 bb(256);

    const bool bigws = ws_size >= (size_t)82 * 1024 * 1024;

    if (bigws) {
        // qb at ws+64MB, wob at ws+80MB: no aliasing -> Q/K/V in ONE dispatch
        // and Wo conversion fused into cvt. 4 launches total.
        unsigned short* qb  = VTp + MB16;            // ws[64:80)
        unsigned short* wob = qb + MB16;             // ws[80:82)
        cvt_kernel<<<dim3(24576 + 4096), bb, 0, stream>>>(query, key_, value, Wq, Wk, Wv, Wo,
                                                          qb, kb, vb, wqb, wkb, wvb, wob);
        gemm_qkv3<<<dim3(256, 1, 3), dim3(512), 0, stream>>>(qb, wqb, bq, Qp,
                                                             kb, wkb, bk, Kp,
                                                             vb, wvb, bv, VTp, qscale);
        attn_kernel<<<dim3(8, 16, 4), bb, 0, stream>>>(Qp, Kp, VTp, Xp);
        gemm_o<<<dim3(256), dim3(512), 0, stream>>>(Xp, wob, bo, out);
    } else {
        // Fallback (verified flow): qb aliases Kp (stream-serialized),
        // wob aliases vb (written after gemm_kv consumed vb). 6 launches.
        unsigned short* qb  = (unsigned short*)d_out;
        unsigned short* wob = vb;
        cvt_kernel<<<dim3(24576 + 3072), bb, 0, stream>>>(query, key_, value, Wq, Wk, Wv, Wo,
                                                          qb, kb, vb, wqb, wkb, wvb, nullptr);
        gemm_q<<<dim3(256), dim3(512), 0, stream>>>(qb, wqb, bq, Qp, qscale);
        gemm_kv<<<dim3(256, 1, 2), dim3(512), 0, stream>>>(kb, wkb, bk, Kp,
                                                           vb, wvb, bv, VTp);
        attn_kernel<<<dim3(8, 16, 4), bb, 0, stream>>>(Qp, Kp, VTp, Xp);
        cvt1_kernel<<<dim3(1024), bb, 0, stream>>>(Wo, wob);
        gemm_o<<<dim3(256), dim3(512), 0, stream>>>(Xp, wob, bo, out);
    }
}

// Round 14
// 298.344 us; speedup vs baseline: 1.3085x; 1.2845x over previous
//
#include <hip/hip_runtime.h>

typedef float floatx4 __attribute__((ext_vector_type(4)));
typedef short bf16x8 __attribute__((ext_vector_type(8)));
typedef const unsigned int __attribute__((address_space(1))) gas_u32;
typedef unsigned int __attribute__((address_space(3))) las_u32;

#if __has_builtin(__builtin_amdgcn_exp2f)
#define EXP2F(x) __builtin_amdgcn_exp2f(x)
#else
#define EXP2F(x) exp2f(x)
#endif

__device__ __forceinline__ unsigned short f2bf(float x) {
    unsigned int u = __float_as_uint(x);
    unsigned int r = u + 0x7fffu + ((u >> 16) & 1u);
    return (unsigned short)(r >> 16);
}

// truncating pack (P>=0; downward bias cancels in O/l ratio).
__device__ __forceinline__ unsigned int pack2bf_t(float lo, float hi) {
#if __has_builtin(__builtin_amdgcn_perm)
    return __builtin_amdgcn_perm(__float_as_uint(hi), __float_as_uint(lo), 0x07060302u);
#else
    return (__float_as_uint(lo) >> 16) | (__float_as_uint(hi) & 0xffff0000u);
#endif
}

__device__ __forceinline__ void g2l16(const void* g, void* l) {
    __builtin_amdgcn_global_load_lds((gas_u32*)(unsigned long long)g,
                                     (las_u32*)(unsigned int)(unsigned long long)l,
                                     16, 0, 0);
}

// fp32 -> bf16, exact-size linear grid (no idle blocks).
__global__ __launch_bounds__(256) void cvt_kernel(
    const float* __restrict__ q, const float* __restrict__ k, const float* __restrict__ v,
    const float* __restrict__ wq, const float* __restrict__ wk, const float* __restrict__ wv,
    const float* __restrict__ wo,
    unsigned short* __restrict__ qb, unsigned short* __restrict__ kb,
    unsigned short* __restrict__ vb, unsigned short* __restrict__ wqb,
    unsigned short* __restrict__ wkb, unsigned short* __restrict__ wvb,
    unsigned short* __restrict__ wob) {
    const int bid = blockIdx.x;
    const float* src;
    unsigned short* dst;
    int off;
    if (bid < 24576) {
        int s = bid >> 13;                       // 0..2
        off = (bid & 8191) * 256 + threadIdx.x;  // < 2097152 exact
        src = (s == 0) ? q : (s == 1) ? k : v;
        dst = (s == 0) ? qb : (s == 1) ? kb : vb;
    } else {
        int r = bid - 24576;
        int s = r >> 10;                         // 0..3
        off = (r & 1023) * 256 + threadIdx.x;    // < 262144 exact
        src = (s == 0) ? wq : (s == 1) ? wk : (s == 2) ? wv : wo;
        dst = (s == 0) ? wqb : (s == 1) ? wkb : (s == 2) ? wvb : wob;
    }
    float4 x = ((const float4*)src)[off];
    ushort4 o;
    o.x = f2bf(x.x); o.y = f2bf(x.y); o.z = f2bf(x.z); o.w = f2bf(x.w);
    ((ushort4*)dst)[off] = o;
}

// Wo fp32 -> bf16 (1M floats). grid 1024. Fallback (small-ws) path only.
__global__ __launch_bounds__(256) void cvt1_kernel(const float* __restrict__ wo,
                                                   unsigned short* __restrict__ wob) {
    int i = blockIdx.x * 256 + threadIdx.x;
    float4 x = ((const float4*)wo)[i];
    ushort4 o;
    o.x = f2bf(x.x); o.y = f2bf(x.y); o.z = f2bf(x.z); o.w = f2bf(x.w);
    ((ushort4*)wob)[i] = o;
}

// -------- 256x128 tile, BK=32, 512 threads (8 waves, 4M x 2N), ----------
// Verified R11 body: tri-buffered LDS 72 KB (2 blocks/CU, 4 waves/SIMD),
// counted s_waitcnt vmcnt(3) (never 0 in loop), ONE raw s_barrier per K-tile,
// T2 XOR-swizzle with 4-slot key (row>>1)&3 (2-way max = free), T5 setprio.
// B-direct variants (R12/R13) refuted: scattered 64B L2 transactions starve
// MFMA regardless of prefetch depth -- LDS staging IS the W-coalescer.
// OUT_MODE: 0 = fp32 out, 1 = bf16 out scaled,
//           2 = VT transpose (swizzled), 3 = K permuted (swizzled).
template <int OUT_MODE>
__device__ __forceinline__ void gemm256_body(const unsigned short* __restrict__ Asrc,
                                             const unsigned short* __restrict__ W,
                                             const float* __restrict__ bias,
                                             void* __restrict__ Cout,
                                             unsigned short* lds, int m0, int n0,
                                             float scale) {
    constexpr int K = 1024, N = 1024;
    constexpr int ABUF = 256 * 32;          // shorts (16 KB)
    constexpr int BUFS = ABUF + 128 * 32;   // 12288 shorts = 24 KB per buffer
    const int t = threadIdx.x;
    const int lane = t & 63, w = t >> 6;
    const int lr = lane & 15, quad = lane >> 4;
    const int wrow = (w & 3) * 64, wcol = (w >> 2) * 64;

    // staging sources: 4 x 16B slots per row (BK=32); source-col pre-swizzled
    // with key (row>>1)&3 so linear LDS dest + XOR'd read is conflict-free.
    const unsigned short* gA[2];
    const unsigned short* gB;
#pragma unroll
    for (int i = 0; i < 2; ++i) {
        int idx = t + 512 * i;          // 0..1023 -> 256 rows x 4 slots
        int row = idx >> 2, sl = idx & 3;
        gA[i] = Asrc + (size_t)(m0 + row) * K + ((sl ^ ((row >> 1) & 3)) * 8);
    }
    {
        int row = t >> 2, sl = t & 3;   // 0..511 -> 128 rows x 4 slots
        gB = W + (size_t)(n0 + row) * K + ((sl ^ ((row >> 1) & 3)) * 8);
    }

    auto STAGE = [&](int buf, int kt) {     // 3 g2l per thread per stage
        unsigned short* dst = lds + buf * BUFS;
#pragma unroll
        for (int i = 0; i < 2; ++i)
            g2l16(gA[i] + kt * 32, dst + (w * 64 + i * 512) * 8);
        g2l16(gB + kt * 32, dst + ABUF + (w * 64) * 8);
    };

    floatx4 acc[4][4];
#pragma unroll
    for (int i = 0; i < 4; ++i)
#pragma unroll
        for (int j = 0; j < 4; ++j) acc[i][j] = (floatx4){0.f, 0.f, 0.f, 0.f};

    const int sc = (quad ^ ((lr >> 1) & 3)) * 8;   // read slot (XOR involution)

    auto COMPUTE = [&](int buf) {
        const unsigned short* Ab = lds + buf * BUFS;
        const unsigned short* Bb = Ab + ABUF;
        bf16x8 af[4], bfr[4];
#pragma unroll
        for (int i = 0; i < 4; ++i)
            af[i] = *(const bf16x8*)&Ab[(wrow + i * 16 + lr) * 32 + sc];
#pragma unroll
        for (int j = 0; j < 4; ++j)
            bfr[j] = *(const bf16x8*)&Bb[(wcol + j * 16 + lr) * 32 + sc];
#pragma unroll
        for (int i = 0; i < 4; ++i)
#pragma unroll
            for (int j = 0; j < 4; ++j) {
                if constexpr (OUT_MODE == 2)
                    acc[i][j] = __builtin_amdgcn_mfma_f32_16x16x32_bf16(bfr[j], af[i], acc[i][j], 0, 0, 0);
                else
                    acc[i][j] = __builtin_amdgcn_mfma_f32_16x16x32_bf16(af[i], bfr[j], acc[i][j], 0, 0, 0);
            }
    };

    // K = 32 tiles of 32. Tri-buffer pipeline, counted vmcnt (3 g2l/stage).
    STAGE(0, 0);
    STAGE(1, 1);
    for (int kt = 0; kt < 32; ++kt) {
        if (kt < 31) {
            asm volatile("s_waitcnt vmcnt(3)" ::: "memory");  // own stage kt done
        } else {
            asm volatile("s_waitcnt vmcnt(0)" ::: "memory");
        }
        __builtin_amdgcn_sched_barrier(0);
        __builtin_amdgcn_s_barrier();      // all waves' stage-kt writes done
        __builtin_amdgcn_sched_barrier(0);
        if (kt + 2 < 32) STAGE((kt + 2) % 3, kt + 2);
        __builtin_amdgcn_s_setprio(1);
        COMPUTE(kt % 3);
        __builtin_amdgcn_s_setprio(0);
    }

    if constexpr (OUT_MODE == 2) {
        const int b = m0 >> 11;
        unsigned short* VT = (unsigned short*)Cout;
#pragma unroll
        for (int i = 0; i < 4; ++i) {
#pragma unroll
            for (int j = 0; j < 4; ++j) {
#pragma unroll
                for (int r = 0; r < 4; ++r) {
                    int d = n0 + wcol + j * 16 + quad * 4 + r;
                    int tok = (m0 & 2047) + wrow + i * 16 + lr;
                    float val = acc[i][j][r] + bias[d];
                    int t6 = tok & 63;
                    int ntok = (tok & ~63) | ((((t6 >> 3) ^ (d & 7)) << 3)) | (t6 & 7);
                    VT[(((size_t)b * 16 + (d >> 6)) * 64 + (d & 63)) * 2048 + ntok] = f2bf(val);
                }
            }
        }
    } else if constexpr (OUT_MODE == 3) {
        unsigned short* C = (unsigned short*)Cout;
#pragma unroll
        for (int i = 0; i < 4; ++i) {
#pragma unroll
            for (int j = 0; j < 4; ++j) {
#pragma unroll
                for (int r = 0; r < 4; ++r) {
                    int row = m0 + wrow + i * 16 + quad * 4 + r;
                    int col = n0 + wcol + j * 16 + lr;
                    float val = acc[i][j][r] + bias[col];
                    int r6 = row & 63;
                    int srow = (r6 & 32) | (((r6 >> 2) & 1) << 4) |
                               (((r6 >> 3) & 3) << 2) | (r6 & 3);
                    int nrow = (row & ~63) | srow;
                    int c6 = col & 63;
                    int ncol = (col & ~63) | ((((c6 >> 3) ^ (srow & 7)) << 3)) | (c6 & 7);
                    C[(size_t)nrow * N + ncol] = f2bf(val);
                }
            }
        }
    } else if constexpr (OUT_MODE == 1) {
        unsigned short* C = (unsigned short*)Cout;
#pragma unroll
        for (int i = 0; i < 4; ++i) {
#pragma unroll
            for (int j = 0; j < 4; ++j) {
#pragma unroll
                for (int r = 0; r < 4; ++r) {
                    int row = m0 + wrow + i * 16 + quad * 4 + r;
                    int col = n0 + wcol + j * 16 + lr;
                    float val = (acc[i][j][r] + bias[col]) * scale;
                    C[(size_t)row * N + col] = f2bf(val);
                }
            }
        }
    } else {
#pragma unroll
        for (int i = 0; i < 4; ++i) {
#pragma unroll
            for (int j = 0; j < 4; ++j) {
#pragma unroll
                for (int r = 0; r < 4; ++r) {
                    int row = m0 + wrow + i * 16 + quad * 4 + r;
                    int col = n0 + wcol + j * 16 + lr;
                    ((float*)Cout)[(size_t)row * N + col] = acc[i][j][r] + bias[col];
                }
            }
        }
    }
}

// XCD-bijective swizzle for 256-block slices (32 m-tiles x 8 n-tiles)
__device__ __forceinline__ void gemm_swz256(int bx, int& m0, int& n0) {
    const int wid = (bx & 7) * 32 + (bx >> 3);  // bijective (256 % 8 == 0)
    m0 = (wid >> 3) * 256;
    n0 = (wid & 7) * 128;
}

// Fused Q+K+V projections, one dispatch. grid (256, 1, 3), 512 threads.
// Safe only when qb does NOT alias Kp (big-ws path).
__global__ __launch_bounds__(512, 4) void gemm_qkv3(
    const unsigned short* __restrict__ qb, const unsigned short* __restrict__ wqb,
    const float* __restrict__ bq, unsigned short* __restrict__ Qp,
    const unsigned short* __restrict__ kb, const unsigned short* __restrict__ wkb,
    const float* __restrict__ bk, unsigned short* __restrict__ Kp,
    const unsigned short* __restrict__ vb, const unsigned short* __restrict__ wvb,
    const float* __restrict__ bv, unsigned short* __restrict__ VTp, float qscale) {
    __shared__ unsigned short lds[3 * 12288];
    int m0, n0;
    gemm_swz256(blockIdx.x, m0, n0);
    if (blockIdx.z == 0)
        gemm256_body<1>(qb, wqb, bq, Qp, lds, m0, n0, qscale);
    else if (blockIdx.z == 1)
        gemm256_body<3>(kb, wkb, bk, Kp, lds, m0, n0, 1.0f);
    else
        gemm256_body<2>(vb, wvb, bv, VTp, lds, m0, n0, 1.0f);
}

// Q projection alone (fallback path). grid (256), 512 threads.
__global__ __launch_bounds__(512, 4) void gemm_q(
    const unsigned short* __restrict__ qb, const unsigned short* __restrict__ wqb,
    const float* __restrict__ bq, unsigned short* __restrict__ Qp, float qscale) {
    __shared__ unsigned short lds[3 * 12288];
    int m0, n0;
    gemm_swz256(blockIdx.x, m0, n0);
    gemm256_body<1>(qb, wqb, bq, Qp, lds, m0, n0, qscale);
}

// K and V projections (fallback path). grid (256, 1, 2), 512 threads.
__global__ __launch_bounds__(512, 4) void gemm_kv(
    const unsigned short* __restrict__ kb, const unsigned short* __restrict__ wkb,
    const float* __restrict__ bk, unsigned short* __restrict__ Kp,
    const unsigned short* __restrict__ vb, const unsigned short* __restrict__ wvb,
    const float* __restrict__ bv, unsigned short* __restrict__ VTp) {
    __shared__ unsigned short lds[3 * 12288];
    int m0, n0;
    gemm_swz256(blockIdx.x, m0, n0);
    if (blockIdx.z == 0)
        gemm256_body<3>(kb, wkb, bk, Kp, lds, m0, n0, 1.0f);
    else
        gemm256_body<2>(vb, wvb, bv, VTp, lds, m0, n0, 1.0f);
}

// O projection. grid (256), 512 threads.
__global__ __launch_bounds__(512, 4) void gemm_o(const unsigned short* __restrict__ A,
                                                 const unsigned short* __restrict__ W,
                                                 const float* __restrict__ bias,
                                                 void* __restrict__ C) {
    __shared__ unsigned short lds[3 * 12288];
    int m0, n0;
    gemm_swz256(blockIdx.x, m0, n0);
    gemm256_body<0>(A, W, bias, C, lds, m0, n0, 1.0f);
}

// Flash attention v4 (verified): 64 q per wave (QBLK=256). K/V pre-permuted +
// XOR-swizzled in GLOBAL memory; bare global_load_lds staging, dbuf, 1 barrier
// per 64-key tile. grid (8 q-tiles, 16 h, 4 b), 256 thr = 4 waves, 64 q/wave.
__global__ __launch_bounds__(256, 2) void attn_kernel(const unsigned short* __restrict__ Qp,
                                                      const unsigned short* __restrict__ Kp,
                                                      const unsigned short* __restrict__ VTp,
                                                      unsigned short* __restrict__ Xp) {
    constexpr int L = 2048, D = 1024;
    __shared__ unsigned short Ks[2][64 * 64];   // permuted+swizzled key tiles
    __shared__ unsigned short Vt[2][64 * 64];   // [d][64 keys], swizzled slots

    const int t = threadIdx.x;
    // XCD swizzle: hw linear id -> work id; 512 % 8 == 0 -> bijective.
    const int hw = blockIdx.x + 8 * blockIdx.y + 128 * blockIdx.z;
    const int wid = (hw & 7) * 64 + (hw >> 3);
    const int q0 = (wid & 7) * 256;
    const int h = (wid >> 3) & 15;
    const int b = wid >> 7;
    const int lane = t & 63;
    const int w = t >> 6;
    const int lr = lane & 15;
    const int quad = lane >> 4;
    const int x7 = lr & 7;

    const size_t kbase = ((size_t)(b * L)) * D + (size_t)h * 64;
    const size_t vtbase = ((size_t)(b * 16 + h)) * 64 * 2048;

    auto stage_async = [&](int buf, int kb2) {
        int k0 = kb2 * 64;
#pragma unroll
        for (int i = 0; i < 2; ++i) {
            int idx = t + 256 * i;
            int row = idx >> 3, c16 = idx & 7;
            g2l16(Kp + kbase + (size_t)(k0 + row) * D + c16 * 8,
                  &Ks[buf][(w * 64 + i * 256) * 8]);
            g2l16(VTp + vtbase + (size_t)row * 2048 + k0 + c16 * 8,
                  &Vt[buf][(w * 64 + i * 256) * 8]);
        }
    };

    stage_async(0, 0);   // fire first tile ASAP

    // Q B-frags: B[k=d][n=q], n=lr -> q = q0 + w*64 + qs*16 + lr, qs in 0..3
    const size_t qbase = ((size_t)(b * L + q0)) * D + (size_t)h * 64;
    bf16x8 bq[4][2];
#pragma unroll
    for (int qs = 0; qs < 4; ++qs)
#pragma unroll
        for (int s2 = 0; s2 < 2; ++s2)
            bq[qs][s2] = *(const bf16x8*)(Qp + qbase + (size_t)(w * 64 + qs * 16 + lr) * D +
                                          s2 * 32 + quad * 8);

    floatx4 o[4][4], ol[4];
#pragma unroll
    for (int qs = 0; qs < 4; ++qs) {
        ol[qs] = (floatx4){0.f, 0.f, 0.f, 0.f};
#pragma unroll
        for (int dt = 0; dt < 4; ++dt) o[qs][dt] = (floatx4){0.f, 0.f, 0.f, 0.f};
    }
    bf16x8 ones;
#pragma unroll
    for (int e = 0; e < 8; ++e) ones[e] = (short)0x3F80;

    __syncthreads();     // first tile resident
    int cur = 0;

    // conflict-free slot indices (shorts offset = slot*8)
    const int kc0 = (quad ^ x7) * 8;
    const int kc1 = ((quad + 4) ^ x7) * 8;

    for (int kb = 0; kb < L / 64; ++kb) {
        if (kb < L / 64 - 1) stage_async(cur ^ 1, kb + 1);

        __builtin_amdgcn_s_setprio(1);
#pragma unroll
        for (int g = 0; g < 2; ++g) {
            bf16x8 akA0 = *(const bf16x8*)&Ks[cur][(g * 32 + lr) * 64 + kc0];
            bf16x8 akA1 = *(const bf16x8*)&Ks[cur][(g * 32 + lr) * 64 + kc1];
            bf16x8 akB0 = *(const bf16x8*)&Ks[cur][(g * 32 + 16 + lr) * 64 + kc0];
            bf16x8 akB1 = *(const bf16x8*)&Ks[cur][(g * 32 + 16 + lr) * 64 + kc1];
            bf16x8 vf[4];
#pragma unroll
            for (int dt = 0; dt < 4; ++dt)
                vf[dt] = *(const bf16x8*)&Vt[cur][(dt * 16 + lr) * 64 +
                                                  (((g * 4 + quad) ^ x7) * 8)];

            const floatx4 z4 = (floatx4){0.f, 0.f, 0.f, 0.f};
#pragma unroll
            for (int qs = 0; qs < 4; ++qs) {
                floatx4 stA = __builtin_amdgcn_mfma_f32_16x16x32_bf16(akA0, bq[qs][0], z4, 0, 0, 0);
                stA = __builtin_amdgcn_mfma_f32_16x16x32_bf16(akA1, bq[qs][1], stA, 0, 0, 0);
                floatx4 stB = __builtin_amdgcn_mfma_f32_16x16x32_bf16(akB0, bq[qs][0], z4, 0, 0, 0);
                stB = __builtin_amdgcn_mfma_f32_16x16x32_bf16(akB1, bq[qs][1], stB, 0, 0, 0);

                // exp(S^T) packed as K=32 A-frag: lane m=q(lr), k = quad*8 + j
                union { unsigned int u[4]; bf16x8 v; } pf;
                pf.u[0] = pack2bf_t(EXP2F(stA[0]), EXP2F(stA[1]));
                pf.u[1] = pack2bf_t(EXP2F(stA[2]), EXP2F(stA[3]));
                pf.u[2] = pack2bf_t(EXP2F(stB[0]), EXP2F(stB[1]));
                pf.u[3] = pack2bf_t(EXP2F(stB[2]), EXP2F(stB[3]));

                ol[qs] = __builtin_amdgcn_mfma_f32_16x16x32_bf16(pf.v, ones, ol[qs], 0, 0, 0);
#pragma unroll
                for (int dt = 0; dt < 4; ++dt)
                    o[qs][dt] = __builtin_amdgcn_mfma_f32_16x16x32_bf16(pf.v, vf[dt],
                                                                        o[qs][dt], 0, 0, 0);
            }
        }
        __builtin_amdgcn_s_setprio(0);

        if (kb < L / 64 - 1) {
            __syncthreads();   // drains this wave's g2l (vmcnt) + joins block
            cur ^= 1;
        }
    }

    // epilogue: D[m=q][n=d]: q = q0 + w*64 + qs*16 + quad*4 + r, d = dt*16 + lr
#pragma unroll
    for (int qs = 0; qs < 4; ++qs) {
#pragma unroll
        for (int r = 0; r < 4; ++r) {
            float inv = 1.0f / ol[qs][r];
            int q = q0 + w * 64 + qs * 16 + quad * 4 + r;
            size_t base = ((size_t)(b * L + q)) * D + (size_t)h * 64;
#pragma unroll
            for (int dt = 0; dt < 4; ++dt)
                Xp[base + dt * 16 + lr] = f2bf(o[qs][dt][r] * inv);
        }
    }
}

extern "C" void kernel_launch(void* const* d_in, const int* in_sizes, int n_in,
                              void* d_out, int out_size, void* d_ws, size_t ws_size,
                              hipStream_t stream) {
    const float* query = (const float*)d_in[0];
    const float* key_  = (const float*)d_in[1];
    const float* value = (const float*)d_in[2];
    const float* Wq = (const float*)d_in[3];
    const float* bq = (const float*)d_in[4];
    const float* Wk = (const float*)d_in[5];
    const float* bk = (const float*)d_in[6];
    const float* Wv = (const float*)d_in[7];
    const float* bv = (const float*)d_in[8];
    const float* Wo = (const float*)d_in[9];
    const float* bo = (const float*)d_in[10];
    float* out = (float*)d_out;

    const size_t MB16 = (size_t)8 * 1024 * 1024;   // 16 MB in ushort units

    // ws base (64 MB): [0:16) Qp | [16:32) kb->Xp | [32:48) vb | [48:64) VTp
    unsigned short* Qp  = (unsigned short*)d_ws;
    unsigned short* kb  = Qp + MB16;
    unsigned short* vb  = kb + MB16;
    unsigned short* VTp = vb + MB16;
    unsigned short* Xp  = kb;
    // d_out scratch: [0:16) Kp | [16:22) wqb,wkb,wvb  (gemm_o overwrites later)
    unsigned short* Kp  = (unsigned short*)d_out;
    unsigned short* wqb = Kp + MB16;
    unsigned short* wkb = wqb + 1024 * 1024;
    unsigned short* wvb = wkb + 1024 * 1024;

    const float qscale = 0.125f * 1.44269504f;
    dim3 bb(256);

    const bool bigws = ws_size >= (size_t)82 * 1024 * 1024;

    if (bigws) {
        // qb at ws+64MB, wob at ws+80MB: no aliasing -> Q/K/V in ONE dispatch
        // and Wo conversion fused into cvt. 4 launches total.
        unsigned short* qb  = VTp + MB16;            // ws[64:80)
        unsigned short* wob = qb + MB16;             // ws[80:82)
        cvt_kernel<<<dim3(24576 + 4096), bb, 0, stream>>>(query, key_, value, Wq, Wk, Wv, Wo,
                                                          qb, kb, vb, wqb, wkb, wvb, wob);
        gemm_qkv3<<<dim3(256, 1, 3), dim3(512), 0, stream>>>(qb, wqb, bq, Qp,
                                                             kb, wkb, bk, Kp,
                                                             vb, wvb, bv, VTp, qscale);
        attn_kernel<<<dim3(8, 16, 4), bb, 0, stream>>>(Qp, Kp, VTp, Xp);
        gemm_o<<<dim3(256), dim3(512), 0, stream>>>(Xp, wob, bo, out);
    } else {
        // Fallback (verified flow): qb aliases Kp (stream-serialized),
        // wob aliases vb (written after gemm_kv consumed vb). 6 launches.
        unsigned short* qb  = (unsigned short*)d_out;
        unsigned short* wob = vb;
        cvt_kernel<<<dim3(24576 + 3072), bb, 0, stream>>>(query, key_, value, Wq, Wk, Wv, Wo,
                                                          qb, kb, vb, wqb, wkb, wvb, nullptr);
        gemm_q<<<dim3(256), dim3(512), 0, stream>>>(qb, wqb, bq, Qp, qscale);
        gemm_kv<<<dim3(256, 1, 2), dim3(512), 0, stream>>>(kb, wkb, bk, Kp,
                                                           vb, wvb, bv, VTp);
        attn_kernel<<<dim3(8, 16, 4), bb, 0, stream>>>(Qp, Kp, VTp, Xp);
        cvt1_kernel<<<dim3(1024), bb, 0, stream>>>(Wo, wob);
        gemm_o<<<dim3(256), dim3(512), 0, stream>>>(Xp, wob, bo, out);
    }
}